// Round 12
// baseline (340.667 us; speedup 1.0000x reference)
//
#include <hip/hip_runtime.h>

#define NPOS 16384
#define NEG  (-1e30f)

// workspace offsets (floats)
#define OFF_FWDH  0
#define OFF_BWDH  1966080
#define OFF_A     3932160
#define OFF_T0    4194304
#define OFF_R     4251904
#define OFF_GSC   4255504
#define OFF_CTR   4255744   // 1 x u32
#define OFF_T1    4260096   // 128*225 tree ping-pong

struct Params {
    const float *data, *fWih, *fWhh, *fbih, *fbhh, *bWih, *bWhh, *bbih, *bbhh;
    const float *h0f, *c0f, *h0b, *c0b, *Yenc, *Zenc, *VW, *Vb, *WW, *Wb;
    const int *tags, *lengths;
    float *ws; float *out;
};

typedef _Float16 half2_t __attribute__((ext_vector_type(2)));

__device__ __forceinline__ half2_t u2h(unsigned int v) {
    return __builtin_bit_cast(half2_t, v);
}
__device__ __forceinline__ unsigned int packh(float a, float b) {
    half2_t h = { (_Float16)a, (_Float16)b };
    return __builtin_bit_cast(unsigned int, h);
}
__device__ __forceinline__ float fdot2_(unsigned int w, unsigned int x, float acc) {
    return __builtin_amdgcn_fdot2(u2h(w), u2h(x), acc, false);
}
__device__ __forceinline__ float sigf(float x) {
    return __builtin_amdgcn_rcpf(1.0f + __expf(-x));
}
__device__ __forceinline__ float tanhf_(float x) {
    return 1.0f - 2.0f * __builtin_amdgcn_rcpf(1.0f + __expf(2.0f * x));
}
__device__ __forceinline__ float lse15(const float* tv) {
    float a0 = fmaxf(tv[0], tv[1]),  a1 = fmaxf(tv[2], tv[3]);
    float a2 = fmaxf(tv[4], tv[5]),  a3 = fmaxf(tv[6], tv[7]);
    float a4 = fmaxf(tv[8], tv[9]),  a5 = fmaxf(tv[10], tv[11]);
    float a6 = fmaxf(tv[12], tv[13]);
    float b0 = fmaxf(a0, a1), b1 = fmaxf(a2, a3), b2 = fmaxf(a4, a5), b3 = fmaxf(a6, tv[14]);
    float mx = fmaxf(fmaxf(b0, b1), fmaxf(b2, b3));
    float e[15];
    #pragma unroll
    for (int i = 0; i < 15; i++) e[i] = __expf(tv[i] - mx);
    float s0 = e[0]+e[1], s1 = e[2]+e[3], s2 = e[4]+e[5], s3 = e[6]+e[7];
    float s4 = e[8]+e[9], s5 = e[10]+e[11], s6 = e[12]+e[13];
    float t0 = s0+s1, t1 = s2+s3, t2 = s4+s5, t3 = s6+e[14];
    return mx + __logf((t0+t1) + (t2+t3));
}

// ================= kA: fp16-dot2 xg + LSTM (r10 version) ====================
// grid (256,2): blockIdx.y = dir. 512 thr = 8 waves; wave wq owns hidden
// units {2wq, 2wq+1} (gates i,f,g,o). lane = position.
__global__ __launch_bounds__(512) void kA(Params p)
{
    __shared__ unsigned int xs2[78*33];   // x fp16-pairs [row][k2], stride 33
    __shared__ float xgT[64*78];          // xg f32 [gate][row]
    __shared__ unsigned int hsh[2*512];   // h fp16-pairs [buf][m2*64+lane]
    __shared__ unsigned int wqx[2048];    // Wih pairs [k2][wq*8+jj]
    __shared__ unsigned int wqh[512];     // Whh pairs [m2][wq*8+jj]
    __shared__ float bq[64];

    const int tid  = threadIdx.x;
    const int lane = tid & 63;
    const int wq   = __builtin_amdgcn_readfirstlane(tid >> 6);
    const int dir  = blockIdx.y;
    const int P0   = blockIdx.x << 6;
    const int dbase = P0 - (dir ? 14 : 0);

    if (blockIdx.x == 0 && dir == 0 && tid == 0)
        ((unsigned int*)(p.ws + OFF_CTR))[0] = 0;

    const float* Wih = dir ? p.bWih : p.fWih;
    const float* Whh = dir ? p.bWhh : p.fWhh;
    const float* bih = dir ? p.bbih : p.fbih;
    const float* bhh = dir ? p.bbhh : p.fbhh;
    const float* h0  = dir ? p.h0b  : p.h0f;
    const float* c0  = dir ? p.c0b  : p.c0f;

    // pack Wih pairs along k: wqx[k2*64 + pi], pi=wq*8+jj <-> gate j
    for (int e = tid; e < 2048; e += 512) {
        int k2 = e >> 6, pi = e & 63;
        int w = pi >> 3, jj = pi & 7;
        int j = ((jj >> 1) << 4) + 2*w + (jj & 1);
        wqx[e] = packh(Wih[j*64 + 2*k2], Wih[j*64 + 2*k2 + 1]);
    }
    if (tid < 512) {
        int m2 = tid >> 6, pi = tid & 63;
        int w = pi >> 3, jj = pi & 7;
        int j = ((jj >> 1) << 4) + 2*w + (jj & 1);
        wqh[tid] = packh(Whh[j*16 + 2*m2], Whh[j*16 + 2*m2 + 1]);
    }
    if (tid < 64) {
        int w = tid >> 3, jj = tid & 7;
        int j = ((jj >> 1) << 4) + 2*w + (jj & 1);
        bq[tid] = bih[j] + bhh[j];
    }
    for (int idx = tid; idx < 78*32; idx += 512) {
        int r = idx >> 5, c = idx & 31;
        int q = dbase + r;
        q = q < 0 ? 0 : (q > NPOS-1 ? NPOS-1 : q);
        float2 x2 = *(const float2*)(p.data + (size_t)q*64 + c*2);
        xs2[r*33 + c] = packh(x2.x, x2.y);
    }
    if (tid < 512) {
        int m2 = tid >> 6;
        hsh[tid] = packh(h0[2*m2], h0[2*m2 + 1]);
    }
    __syncthreads();

    // xg = x @ Wih^T + b, rows 0..77 -> xgT (f32)
    #pragma unroll
    for (int pass = 0; pass < 2; pass++) {
        int r = pass*64 + lane;
        if (r < 78) {
            float acc[8];
            #pragma unroll
            for (int jj = 0; jj < 8; jj++) acc[jj] = bq[wq*8 + jj];
            #pragma unroll 8
            for (int k2 = 0; k2 < 32; k2++) {
                unsigned int xp = xs2[r*33 + k2];
                uint4 w0 = *(const uint4*)&wqx[k2*64 + wq*8];
                uint4 w1 = *(const uint4*)&wqx[k2*64 + wq*8 + 4];
                acc[0] = fdot2_(w0.x, xp, acc[0]);
                acc[1] = fdot2_(w0.y, xp, acc[1]);
                acc[2] = fdot2_(w0.z, xp, acc[2]);
                acc[3] = fdot2_(w0.w, xp, acc[3]);
                acc[4] = fdot2_(w1.x, xp, acc[4]);
                acc[5] = fdot2_(w1.y, xp, acc[5]);
                acc[6] = fdot2_(w1.z, xp, acc[6]);
                acc[7] = fdot2_(w1.w, xp, acc[7]);
            }
            #pragma unroll
            for (int jj = 0; jj < 8; jj++) xgT[(wq*8 + jj)*78 + r] = acc[jj];
        }
    }
    float cv0 = c0[wq*2], cv1 = c0[wq*2 + 1];
    unsigned int* outH = (unsigned int*)(p.ws + (dir ? OFF_BWDH : OFF_FWDH));
    __syncthreads();

    int buf = 0;
    for (int d = 0; d < 15; d++) {
        const int row = dir ? (lane + 14 - d) : (lane + d);
        float part[8];
        #pragma unroll
        for (int jj = 0; jj < 8; jj++) part[jj] = xgT[(wq*8 + jj)*78 + row];
        #pragma unroll
        for (int m2 = 0; m2 < 8; m2++) {
            unsigned int hp = hsh[buf*512 + m2*64 + lane];
            uint4 w0 = *(const uint4*)&wqh[m2*64 + wq*8];
            uint4 w1 = *(const uint4*)&wqh[m2*64 + wq*8 + 4];
            part[0] = fdot2_(w0.x, hp, part[0]);
            part[1] = fdot2_(w0.y, hp, part[1]);
            part[2] = fdot2_(w0.z, hp, part[2]);
            part[3] = fdot2_(w0.w, hp, part[3]);
            part[4] = fdot2_(w1.x, hp, part[4]);
            part[5] = fdot2_(w1.y, hp, part[5]);
            part[6] = fdot2_(w1.z, hp, part[6]);
            part[7] = fdot2_(w1.w, hp, part[7]);
        }
        float cn0 = sigf(part[2])*cv0 + sigf(part[0])*tanhf_(part[4]);
        float cn1 = sigf(part[3])*cv1 + sigf(part[1])*tanhf_(part[5]);
        cv0 = cn0; cv1 = cn1;
        float h0v = sigf(part[6])*tanhf_(cn0);
        float h1v = sigf(part[7])*tanhf_(cn1);
        unsigned int pk = packh(h0v, h1v);
        hsh[(buf^1)*512 + wq*64 + lane] = pk;
        outH[((size_t)d*NPOS + P0 + lane)*8 + wq] = pk;
        __syncthreads();
        buf ^= 1;
    }
}

// ================= kBCD: scores + A + chunk DP + last-block tree + out ======
// 256 blocks x 1024 thr; block c owns positions P0..P0+63.
// After writing T0[c], last block tree-combines all 256 matrices (global
// ping-pong, 8 levels) and computes the final output.
__global__ __launch_bounds__(1024) void kBCD(Params p)
{
    __shared__ float As[64*17];          // A[pl][d], stride 17
    __shared__ unsigned int VWh[256];    // VW fp16 pairs [h][j2]
    __shared__ float zbl[240];
    __shared__ float EY[240];            // exp(2 * Y_enc @ V2^T)
    __shared__ float red[16];
    __shared__ int lastFlag;
    const int tid = threadIdx.x;
    const int P0  = blockIdx.x << 6;
    float* ws = p.ws;

    if (tid < 240) {
        int y = tid >> 4, h = tid & 15;
        float acc = 0.f;
        for (int t = 0; t < 32; t++) acc += p.Yenc[y*32 + t] * p.VW[h*68 + 32 + t];
        EY[tid] = __expf(acc + acc);
        float z = p.Vb[h];
        for (int u = 0; u < 4; u++) z += p.Zenc[y*4 + u] * p.VW[h*68 + 64 + u];
        zbl[tid] = z;
    }
    if (tid < 256) {
        int h = tid >> 4, j2 = tid & 15;
        int col = (j2 < 8) ? 2*j2 : 16 + 2*(j2 - 8);
        VWh[tid] = packh(p.VW[h*68 + col], p.VW[h*68 + col + 1]);
    }
    __syncthreads();

    const int pl = tid & 63;
    const int d  = tid >> 6;          // 0..15 (15 = pad)
    const int pp = P0 + pl;
    float Aval = NEG;
    if (d < 15 && pp >= d) {
        const uint4* fptr = (const uint4*)((const unsigned int*)(ws + OFF_FWDH)
                            + ((size_t)d*NPOS + (pp - d))*8);
        const uint4* bptr = (const uint4*)((const unsigned int*)(ws + OFF_BWDH)
                            + ((size_t)d*NPOS + pp)*8);
        uint4 f0 = fptr[0], f1 = fptr[1];
        uint4 b0 = bptr[0], b1 = bptr[1];
        unsigned int fp_[8] = {f0.x, f0.y, f0.z, f0.w, f1.x, f1.y, f1.z, f1.w};
        unsigned int bp_[8] = {b0.x, b0.y, b0.z, b0.w, b1.x, b1.y, b1.z, b1.w};
        float E[16], w2[16], wsum = 0.f;
        #pragma unroll
        for (int h = 0; h < 16; h++) {
            float acc = zbl[d*16 + h];
            uint4 va = *(const uint4*)&VWh[h*16];
            uint4 vb = *(const uint4*)&VWh[h*16 + 4];
            uint4 vc = *(const uint4*)&VWh[h*16 + 8];
            uint4 vd = *(const uint4*)&VWh[h*16 + 12];
            acc = fdot2_(va.x, fp_[0], acc); acc = fdot2_(va.y, fp_[1], acc);
            acc = fdot2_(va.z, fp_[2], acc); acc = fdot2_(va.w, fp_[3], acc);
            acc = fdot2_(vb.x, fp_[4], acc); acc = fdot2_(vb.y, fp_[5], acc);
            acc = fdot2_(vb.z, fp_[6], acc); acc = fdot2_(vb.w, fp_[7], acc);
            acc = fdot2_(vc.x, bp_[0], acc); acc = fdot2_(vc.y, bp_[1], acc);
            acc = fdot2_(vc.z, bp_[2], acc); acc = fdot2_(vc.w, bp_[3], acc);
            acc = fdot2_(vd.x, bp_[4], acc); acc = fdot2_(vd.y, bp_[5], acc);
            acc = fdot2_(vd.z, bp_[6], acc); acc = fdot2_(vd.w, bp_[7], acc);
            E[h] = __expf(acc + acc);
            float w = p.WW[h];
            w2[h] = -2.0f * w;
            wsum += w;
        }
        const float cst = p.Wb[0] + wsum;
        float sc[15];
        #pragma unroll
        for (int y = 0; y < 15; y++) {
            float a = 0.f;
            #pragma unroll
            for (int h = 0; h < 16; h++)
                a = fmaf(w2[h], __builtin_amdgcn_rcpf(1.0f + E[h]*EY[y*16 + h]), a);
            sc[y] = cst + a;
        }
        Aval = lse15(sc);
        if (pp == d && pp < 15) {
            float* gsc = ws + OFF_GSC;
            #pragma unroll
            for (int y = 0; y < 15; y++) gsc[pp*15 + y] = sc[y];
        }
    }
    As[pl*17 + d] = Aval;
    __syncthreads();

    // chunk DP: 64 steps, threads 0..14
    if (tid < 15) {
        const int j = tid;
        float s[15];
        #pragma unroll
        for (int i = 0; i < 15; i++) s[i] = (i == j) ? 0.f : NEG;
        #pragma unroll 4
        for (int t = 0; t < 64; t++) {
            float tv[15];
            #pragma unroll
            for (int i = 0; i < 15; i++) tv[i] = s[i] + As[t*17 + i];
            float nw = lse15(tv);
            #pragma unroll
            for (int i = 14; i > 0; i--) s[i] = s[i-1];
            s[0] = nw;
        }
        float* T0 = ws + OFF_T0;
        #pragma unroll
        for (int i = 0; i < 15; i++) T0[blockIdx.x*225 + i*15 + j] = s[i];
    }
    __syncthreads();
    __threadfence();   // release T0[bid] (+ gsc for block 0)
    unsigned int* ctr = (unsigned int*)(ws + OFF_CTR);
    if (tid == 0) {
        unsigned int old = __hip_atomic_fetch_add(&ctr[0], 1u, __ATOMIC_ACQ_REL,
                                                  __HIP_MEMORY_SCOPE_AGENT);
        lastFlag = (old == 255u);
    }
    __syncthreads();
    if (!lastFlag) return;
    __threadfence();   // acquire all T0 + gsc

    // ---- last block: binary-tree combine of 256 matrices (global ping-pong)
    float* bufA = ws + OFF_T0;
    float* bufB = ws + OFF_T1;
    const float* src = bufA;
    float* dst = bufB;
    for (int n = 256; n > 1; n >>= 1) {
        int half = n >> 1;
        for (int e = tid; e < half*225; e += 1024) {
            int cpair = e / 225, r = e % 225;
            int i2 = r / 15, j2 = r % 15;
            const float* lo = src + (2*cpair)*225;
            const float* hi = src + (2*cpair + 1)*225;
            float tv[15];
            #pragma unroll
            for (int k = 0; k < 15; k++) tv[k] = hi[i2*15 + k] + lo[k*15 + j2];
            dst[e] = lse15(tv);
        }
        __syncthreads();   // same-CU global RAW: safe across barrier
        const float* ts = dst; dst = (dst == bufB) ? bufA : bufB;
        src = ts;
    }
    // final matrix at src; logZ = src[0]
    const float* gsc = ws + OFF_GSC;
    float loc = 0.f;
    for (int s = tid; s < 2048; s += 1024) {
        int len = p.lengths[s];
        if (len < 15) loc += gsc[(len-1)*15 + p.tags[s]];
    }
    #pragma unroll
    for (int off = 32; off > 0; off >>= 1) loc += __shfl_down(loc, off);
    if ((tid & 63) == 0) red[tid >> 6] = loc;
    __syncthreads();
    if (tid == 0) {
        float ind = 0.f;
        #pragma unroll
        for (int w = 0; w < 16; w++) ind += red[w];
        p.out[0] = src[0] - ind;
    }
}

// ================= launcher =================================================
extern "C" void kernel_launch(void* const* d_in, const int* in_sizes, int n_in,
                              void* d_out, int out_size, void* d_ws, size_t ws_size,
                              hipStream_t stream)
{
    Params prm;
    prm.data = (const float*)d_in[0];
    prm.fWih = (const float*)d_in[1];
    prm.fWhh = (const float*)d_in[2];
    prm.fbih = (const float*)d_in[3];
    prm.fbhh = (const float*)d_in[4];
    prm.bWih = (const float*)d_in[5];
    prm.bWhh = (const float*)d_in[6];
    prm.bbih = (const float*)d_in[7];
    prm.bbhh = (const float*)d_in[8];
    prm.h0f  = (const float*)d_in[9];
    prm.c0f  = (const float*)d_in[10];
    prm.h0b  = (const float*)d_in[11];
    prm.c0b  = (const float*)d_in[12];
    prm.Yenc = (const float*)d_in[13];
    prm.Zenc = (const float*)d_in[14];
    prm.VW   = (const float*)d_in[15];
    prm.Vb   = (const float*)d_in[16];
    prm.WW   = (const float*)d_in[17];
    prm.Wb   = (const float*)d_in[18];
    prm.tags    = (const int*)d_in[19];
    prm.lengths = (const int*)d_in[20];
    prm.ws  = (float*)d_ws;
    prm.out = (float*)d_out;

    hipLaunchKernelGGL(kA,   dim3(256, 2), dim3(512),  0, stream, prm);
    hipLaunchKernelGGL(kBCD, dim3(256),    dim3(1024), 0, stream, prm);
}

// Round 13
// 187.440 us; speedup vs baseline: 1.8175x; 1.8175x over previous
//
#include <hip/hip_runtime.h>

#define NPOS 16384
#define NEG  (-1e30f)

// workspace offsets (floats)
#define OFF_FWDH  0
#define OFF_BWDH  1966080
#define OFF_A     3932160
#define OFF_T0    4194304
#define OFF_R     4251904
#define OFF_GSC   4255504
#define OFF_CTR   4255744   // 1 x u32

struct Params {
    const float *data, *fWih, *fWhh, *fbih, *fbhh, *bWih, *bWhh, *bbih, *bbhh;
    const float *h0f, *c0f, *h0b, *c0b, *Yenc, *Zenc, *VW, *Vb, *WW, *Wb;
    const int *tags, *lengths;
    float *ws; float *out;
};

typedef _Float16 half2_t __attribute__((ext_vector_type(2)));

__device__ __forceinline__ half2_t u2h(unsigned int v) {
    return __builtin_bit_cast(half2_t, v);
}
__device__ __forceinline__ unsigned int packh(float a, float b) {
    half2_t h = { (_Float16)a, (_Float16)b };
    return __builtin_bit_cast(unsigned int, h);
}
__device__ __forceinline__ float fdot2_(unsigned int w, unsigned int x, float acc) {
    return __builtin_amdgcn_fdot2(u2h(w), u2h(x), acc, false);
}
__device__ __forceinline__ float sigf(float x) {
    return __builtin_amdgcn_rcpf(1.0f + __expf(-x));
}
__device__ __forceinline__ float tanhf_(float x) {
    return 1.0f - 2.0f * __builtin_amdgcn_rcpf(1.0f + __expf(2.0f * x));
}
__device__ __forceinline__ float lse15(const float* tv) {
    float a0 = fmaxf(tv[0], tv[1]),  a1 = fmaxf(tv[2], tv[3]);
    float a2 = fmaxf(tv[4], tv[5]),  a3 = fmaxf(tv[6], tv[7]);
    float a4 = fmaxf(tv[8], tv[9]),  a5 = fmaxf(tv[10], tv[11]);
    float a6 = fmaxf(tv[12], tv[13]);
    float b0 = fmaxf(a0, a1), b1 = fmaxf(a2, a3), b2 = fmaxf(a4, a5), b3 = fmaxf(a6, tv[14]);
    float mx = fmaxf(fmaxf(b0, b1), fmaxf(b2, b3));
    float e[15];
    #pragma unroll
    for (int i = 0; i < 15; i++) e[i] = __expf(tv[i] - mx);
    float s0 = e[0]+e[1], s1 = e[2]+e[3], s2 = e[4]+e[5], s3 = e[6]+e[7];
    float s4 = e[8]+e[9], s5 = e[10]+e[11], s6 = e[12]+e[13];
    float t0 = s0+s1, t1 = s2+s3, t2 = s4+s5, t3 = s6+e[14];
    return mx + __logf((t0+t1) + (t2+t3));
}

// ================= kA: fp16-dot2 xg + LSTM ==================================
// grid (256,2): blockIdx.y = dir. 512 thr = 8 waves; wave wq owns hidden
// units {2wq, 2wq+1} (gates i,f,g,o). lane = position. All contractions via
// v_dot2_f32_f16 on fp16 pairs (no unpack ops in the hot loops).
__global__ __launch_bounds__(512) void kA(Params p)
{
    __shared__ unsigned int xs2[78*33];   // x fp16-pairs [row][k2], stride 33
    __shared__ float xgT[64*78];          // xg f32 [gate][row]
    __shared__ unsigned int hsh[2*512];   // h fp16-pairs [buf][m2*64+lane]
    __shared__ unsigned int wqx[2048];    // Wih pairs [k2][wq*8+jj]
    __shared__ unsigned int wqh[512];     // Whh pairs [m2][wq*8+jj]
    __shared__ float bq[64];

    const int tid  = threadIdx.x;
    const int lane = tid & 63;
    const int wq   = __builtin_amdgcn_readfirstlane(tid >> 6);
    const int dir  = blockIdx.y;
    const int P0   = blockIdx.x << 6;
    const int dbase = P0 - (dir ? 14 : 0);

    if (blockIdx.x == 0 && dir == 0 && tid == 0)
        ((unsigned int*)(p.ws + OFF_CTR))[0] = 0;

    const float* Wih = dir ? p.bWih : p.fWih;
    const float* Whh = dir ? p.bWhh : p.fWhh;
    const float* bih = dir ? p.bbih : p.fbih;
    const float* bhh = dir ? p.bbhh : p.fbhh;
    const float* h0  = dir ? p.h0b  : p.h0f;
    const float* c0  = dir ? p.c0b  : p.c0f;

    // pack Wih pairs along k: wqx[k2*64 + pi], pi=wq*8+jj <-> gate j
    for (int e = tid; e < 2048; e += 512) {
        int k2 = e >> 6, pi = e & 63;
        int w = pi >> 3, jj = pi & 7;
        int j = ((jj >> 1) << 4) + 2*w + (jj & 1);
        wqx[e] = packh(Wih[j*64 + 2*k2], Wih[j*64 + 2*k2 + 1]);
    }
    if (tid < 512) {
        int m2 = tid >> 6, pi = tid & 63;
        int w = pi >> 3, jj = pi & 7;
        int j = ((jj >> 1) << 4) + 2*w + (jj & 1);
        wqh[tid] = packh(Whh[j*16 + 2*m2], Whh[j*16 + 2*m2 + 1]);
    }
    if (tid < 64) {
        int w = tid >> 3, jj = tid & 7;
        int j = ((jj >> 1) << 4) + 2*w + (jj & 1);
        bq[tid] = bih[j] + bhh[j];
    }
    for (int idx = tid; idx < 78*32; idx += 512) {
        int r = idx >> 5, c = idx & 31;
        int q = dbase + r;
        q = q < 0 ? 0 : (q > NPOS-1 ? NPOS-1 : q);
        float2 x2 = *(const float2*)(p.data + (size_t)q*64 + c*2);
        xs2[r*33 + c] = packh(x2.x, x2.y);
    }
    if (tid < 512) {
        int m2 = tid >> 6;
        hsh[tid] = packh(h0[2*m2], h0[2*m2 + 1]);
    }
    __syncthreads();

    // xg = x @ Wih^T + b, rows 0..77 -> xgT (f32)
    #pragma unroll
    for (int pass = 0; pass < 2; pass++) {
        int r = pass*64 + lane;
        if (r < 78) {
            float acc[8];
            #pragma unroll
            for (int jj = 0; jj < 8; jj++) acc[jj] = bq[wq*8 + jj];
            #pragma unroll 8
            for (int k2 = 0; k2 < 32; k2++) {
                unsigned int xp = xs2[r*33 + k2];
                uint4 w0 = *(const uint4*)&wqx[k2*64 + wq*8];
                uint4 w1 = *(const uint4*)&wqx[k2*64 + wq*8 + 4];
                acc[0] = fdot2_(w0.x, xp, acc[0]);
                acc[1] = fdot2_(w0.y, xp, acc[1]);
                acc[2] = fdot2_(w0.z, xp, acc[2]);
                acc[3] = fdot2_(w0.w, xp, acc[3]);
                acc[4] = fdot2_(w1.x, xp, acc[4]);
                acc[5] = fdot2_(w1.y, xp, acc[5]);
                acc[6] = fdot2_(w1.z, xp, acc[6]);
                acc[7] = fdot2_(w1.w, xp, acc[7]);
            }
            #pragma unroll
            for (int jj = 0; jj < 8; jj++) xgT[(wq*8 + jj)*78 + r] = acc[jj];
        }
    }
    float cv0 = c0[wq*2], cv1 = c0[wq*2 + 1];
    unsigned int* outH = (unsigned int*)(p.ws + (dir ? OFF_BWDH : OFF_FWDH));
    __syncthreads();

    int buf = 0;
    for (int d = 0; d < 15; d++) {
        const int row = dir ? (lane + 14 - d) : (lane + d);
        float part[8];
        #pragma unroll
        for (int jj = 0; jj < 8; jj++) part[jj] = xgT[(wq*8 + jj)*78 + row];
        #pragma unroll
        for (int m2 = 0; m2 < 8; m2++) {
            unsigned int hp = hsh[buf*512 + m2*64 + lane];
            uint4 w0 = *(const uint4*)&wqh[m2*64 + wq*8];
            uint4 w1 = *(const uint4*)&wqh[m2*64 + wq*8 + 4];
            part[0] = fdot2_(w0.x, hp, part[0]);
            part[1] = fdot2_(w0.y, hp, part[1]);
            part[2] = fdot2_(w0.z, hp, part[2]);
            part[3] = fdot2_(w0.w, hp, part[3]);
            part[4] = fdot2_(w1.x, hp, part[4]);
            part[5] = fdot2_(w1.y, hp, part[5]);
            part[6] = fdot2_(w1.z, hp, part[6]);
            part[7] = fdot2_(w1.w, hp, part[7]);
        }
        float cn0 = sigf(part[2])*cv0 + sigf(part[0])*tanhf_(part[4]);
        float cn1 = sigf(part[3])*cv1 + sigf(part[1])*tanhf_(part[5]);
        cv0 = cn0; cv1 = cn1;
        float h0v = sigf(part[6])*tanhf_(cn0);
        float h1v = sigf(part[7])*tanhf_(cn1);
        unsigned int pk = packh(h0v, h1v);
        hsh[(buf^1)*512 + wq*64 + lane] = pk;
        outH[((size_t)d*NPOS + P0 + lane)*8 + wq] = pk;
        __syncthreads();
        buf ^= 1;
    }
}

// ================= kBC: scores + A (in LDS) + chunk DP ======================
// 256 blocks x 1024 thr; block c owns positions P0..P0+63, entries (pl, d).
__global__ __launch_bounds__(1024) void kBC(Params p)
{
    __shared__ float As[64*17];          // A[pl][d], stride 17 (conflict-free)
    __shared__ unsigned int VWh[256];    // VW fp16 pairs [h][j2], j2: 0-7 fwd, 8-15 bwd
    __shared__ float zbl[240];
    __shared__ float EY[240];            // exp(2 * Y_enc @ V2^T)
    const int tid = threadIdx.x;
    const int P0  = blockIdx.x << 6;
    float* ws = p.ws;

    if (tid < 240) {
        int y = tid >> 4, h = tid & 15;
        float acc = 0.f;
        for (int t = 0; t < 32; t++) acc += p.Yenc[y*32 + t] * p.VW[h*68 + 32 + t];
        EY[tid] = __expf(acc + acc);
        float z = p.Vb[h];
        for (int u = 0; u < 4; u++) z += p.Zenc[y*4 + u] * p.VW[h*68 + 64 + u];
        zbl[tid] = z;
    }
    if (tid < 256) {
        int h = tid >> 4, j2 = tid & 15;
        int col = (j2 < 8) ? 2*j2 : 16 + 2*(j2 - 8);
        VWh[tid] = packh(p.VW[h*68 + col], p.VW[h*68 + col + 1]);
    }
    __syncthreads();

    const int pl = tid & 63;
    const int d  = tid >> 6;          // 0..15 (15 = pad)
    const int pp = P0 + pl;
    float Aval = NEG;
    if (d < 15 && pp >= d) {
        const uint4* fptr = (const uint4*)((const unsigned int*)(ws + OFF_FWDH)
                            + ((size_t)d*NPOS + (pp - d))*8);
        const uint4* bptr = (const uint4*)((const unsigned int*)(ws + OFF_BWDH)
                            + ((size_t)d*NPOS + pp)*8);
        uint4 f0 = fptr[0], f1 = fptr[1];
        uint4 b0 = bptr[0], b1 = bptr[1];
        unsigned int fp_[8] = {f0.x, f0.y, f0.z, f0.w, f1.x, f1.y, f1.z, f1.w};
        unsigned int bp_[8] = {b0.x, b0.y, b0.z, b0.w, b1.x, b1.y, b1.z, b1.w};
        float E[16], w2[16], wsum = 0.f;
        #pragma unroll
        for (int h = 0; h < 16; h++) {
            float acc = zbl[d*16 + h];
            uint4 va = *(const uint4*)&VWh[h*16];
            uint4 vb = *(const uint4*)&VWh[h*16 + 4];
            uint4 vc = *(const uint4*)&VWh[h*16 + 8];
            uint4 vd = *(const uint4*)&VWh[h*16 + 12];
            acc = fdot2_(va.x, fp_[0], acc); acc = fdot2_(va.y, fp_[1], acc);
            acc = fdot2_(va.z, fp_[2], acc); acc = fdot2_(va.w, fp_[3], acc);
            acc = fdot2_(vb.x, fp_[4], acc); acc = fdot2_(vb.y, fp_[5], acc);
            acc = fdot2_(vb.z, fp_[6], acc); acc = fdot2_(vb.w, fp_[7], acc);
            acc = fdot2_(vc.x, bp_[0], acc); acc = fdot2_(vc.y, bp_[1], acc);
            acc = fdot2_(vc.z, bp_[2], acc); acc = fdot2_(vc.w, bp_[3], acc);
            acc = fdot2_(vd.x, bp_[4], acc); acc = fdot2_(vd.y, bp_[5], acc);
            acc = fdot2_(vd.z, bp_[6], acc); acc = fdot2_(vd.w, bp_[7], acc);
            E[h] = __expf(acc + acc);
            float w = p.WW[h];
            w2[h] = -2.0f * w;
            wsum += w;
        }
        const float cst = p.Wb[0] + wsum;
        float sc[15];
        #pragma unroll
        for (int y = 0; y < 15; y++) {
            float a = 0.f;
            #pragma unroll
            for (int h = 0; h < 16; h++)
                a = fmaf(w2[h], __builtin_amdgcn_rcpf(1.0f + E[h]*EY[y*16 + h]), a);
            sc[y] = cst + a;
        }
        Aval = lse15(sc);
        if (pp == d && pp < 15) {
            float* gsc = ws + OFF_GSC;
            #pragma unroll
            for (int y = 0; y < 15; y++) gsc[pp*15 + y] = sc[y];
        }
    }
    As[pl*17 + d] = Aval;
    __syncthreads();

    // chunk DP: 64 steps, threads 0..14
    if (tid < 15) {
        const int j = tid;
        float s[15];
        #pragma unroll
        for (int i = 0; i < 15; i++) s[i] = (i == j) ? 0.f : NEG;
        #pragma unroll 4
        for (int t = 0; t < 64; t++) {
            float tv[15];
            #pragma unroll
            for (int i = 0; i < 15; i++) tv[i] = s[i] + As[t*17 + i];
            float nw = lse15(tv);
            #pragma unroll
            for (int i = 14; i > 0; i--) s[i] = s[i-1];
            s[0] = nw;
        }
        float* T0 = ws + OFF_T0;
        #pragma unroll
        for (int i = 0; i < 15; i++) T0[blockIdx.x*225 + i*15 + j] = s[i];
    }
}

// ================= kDE: combine 16x16 + last-block final =====================
__global__ __launch_bounds__(256) void kDE(Params p)
{
    __shared__ float sm[4084];
    __shared__ int lastFlag;
    const int tid = threadIdx.x;
    const int b   = blockIdx.x;
    unsigned int* ctr = (unsigned int*)(p.ws + OFF_CTR);

    {
        float* Rm = sm;   // 240, stride 16
        const float* T0 = p.ws + OFF_T0;
        const int e = tid, i2 = e / 15, j2 = e % 15;
        const int c0 = b * 16;
        if (e < 225) Rm[i2*16 + j2] = T0[c0*225 + e];
        __syncthreads();
        for (int t = 1; t < 16; t++) {
            float nw = 0.f;
            if (e < 225) {
                const float* Trow = T0 + (c0 + t)*225 + i2*15;
                float tv[15];
                #pragma unroll
                for (int k = 0; k < 15; k++) tv[k] = Trow[k] + Rm[k*16 + j2];
                nw = lse15(tv);
            }
            __syncthreads();
            if (e < 225) Rm[i2*16 + j2] = nw;
            __syncthreads();
        }
        if (e < 225) p.ws[OFF_R + b*225 + e] = Rm[i2*16 + j2];
    }
    __syncthreads();
    __threadfence();
    if (tid == 0) {
        unsigned int old = __hip_atomic_fetch_add(&ctr[0], 1u, __ATOMIC_ACQ_REL,
                                                  __HIP_MEMORY_SCOPE_AGENT);
        lastFlag = (old == 15u);
    }
    __syncthreads();
    if (!lastFlag) return;
    __threadfence();

    {
        float* RA  = sm;           // 16*240
        float* G   = sm + 3840;    // 240
        float* red = sm + 4080;    // 4
        const float* Rg = p.ws + OFF_R;
        for (int idx = tid; idx < 16*225; idx += 256) {
            int t = idx / 225, r = idx % 225;
            RA[t*240 + (r/15)*16 + (r%15)] = Rg[idx];
        }
        __syncthreads();
        const int e = tid, i2 = e / 15, j2 = e % 15;
        if (e < 225) G[i2*16 + j2] = RA[i2*16 + j2];
        __syncthreads();
        for (int t = 1; t < 16; t++) {
            float nw = 0.f;
            if (e < 225) {
                float tv[15];
                #pragma unroll
                for (int k = 0; k < 15; k++) tv[k] = RA[t*240 + i2*16 + k] + G[k*16 + j2];
                nw = lse15(tv);
            }
            __syncthreads();
            if (e < 225) G[i2*16 + j2] = nw;
            __syncthreads();
        }
        const float* gsc = p.ws + OFF_GSC;
        float loc = 0.f;
        for (int s = tid; s < 2048; s += 256) {
            int len = p.lengths[s];
            if (len < 15) loc += gsc[(len-1)*15 + p.tags[s]];
        }
        #pragma unroll
        for (int off = 32; off > 0; off >>= 1) loc += __shfl_down(loc, off);
        if ((tid & 63) == 0) red[tid >> 6] = loc;
        __syncthreads();
        if (tid == 0) {
            float ind = red[0] + red[1] + red[2] + red[3];
            p.out[0] = G[0] - ind;
        }
    }
}

// ================= launcher =================================================
extern "C" void kernel_launch(void* const* d_in, const int* in_sizes, int n_in,
                              void* d_out, int out_size, void* d_ws, size_t ws_size,
                              hipStream_t stream)
{
    Params prm;
    prm.data = (const float*)d_in[0];
    prm.fWih = (const float*)d_in[1];
    prm.fWhh = (const float*)d_in[2];
    prm.fbih = (const float*)d_in[3];
    prm.fbhh = (const float*)d_in[4];
    prm.bWih = (const float*)d_in[5];
    prm.bWhh = (const float*)d_in[6];
    prm.bbih = (const float*)d_in[7];
    prm.bbhh = (const float*)d_in[8];
    prm.h0f  = (const float*)d_in[9];
    prm.c0f  = (const float*)d_in[10];
    prm.h0b  = (const float*)d_in[11];
    prm.c0b  = (const float*)d_in[12];
    prm.Yenc = (const float*)d_in[13];
    prm.Zenc = (const float*)d_in[14];
    prm.VW   = (const float*)d_in[15];
    prm.Vb   = (const float*)d_in[16];
    prm.WW   = (const float*)d_in[17];
    prm.Wb   = (const float*)d_in[18];
    prm.tags    = (const int*)d_in[19];
    prm.lengths = (const int*)d_in[20];
    prm.ws  = (float*)d_ws;
    prm.out = (float*)d_out;

    hipLaunchKernelGGL(kA,  dim3(256, 2), dim3(512),  0, stream, prm);
    hipLaunchKernelGGL(kBC, dim3(256),    dim3(1024), 0, stream, prm);
    hipLaunchKernelGGL(kDE, dim3(16),     dim3(256),  0, stream, prm);
}